// Round 17
// baseline (321.998 us; speedup 1.0000x reference)
//
#include <hip/hip_runtime.h>
#include <math.h>

#define BB 8192
#define DD 2048
#define BN_EPS 1e-5f
#define NB 512          // pass blocks
#define RPB 16          // rows per pass block
#define PASS_THR 512

// ws layout (floats)
#define OFF_T  0                    // tbuf[4][BB]   (t_k = s_{k-1})
#define OFF_A  (4 * BB)             // a[DD]
#define OFF_C  (OFF_A + DD)         // c[4][DD]
#define OFF_E  (OFF_C + 4 * DD)     // e[DD]
#define OFF_M1 (OFF_E + DD)         // M1[5][DD]
#define OFF_M2 (OFF_M1 + 5 * DD)    // M2[15][DD]
#define OFF_MID (OFF_M2 + 15 * DD)  // mid[16][6][DD]
#define OFF_P  (OFF_MID + 16 * 6 * DD)      // partials[NB][nv][DD]
#define OFF_CNT (OFF_P + NB * 6 * DD)       // 4 unsigned counters

__host__ __device__ constexpr int P2(int j, int k) { return k * (k + 1) / 2 + j; }

// One pass over x per layer (r16-verified: fold t-combination before the
// butterfly -> ONE shfl reduction per row).
template <int LAY>
__global__ __launch_bounds__(PASS_THR) void k_pass(
    const float* __restrict__ x, const float* __restrict__ w4, float* __restrict__ ws)
{
    constexpr int NV = (LAY == 0) ? 5 : (3 + LAY);
    const float* avec = ws + OFF_A;
    const float* cvec = ws + OFF_C;
    const float* evec = ws + OFF_E;
    float* tbuf     = ws + OFF_T;
    float* partials = ws + OFF_P;

    const int t    = threadIdx.x;
    const int lane = t & 63;
    const int wv   = t >> 6;            // 8 waves
    const int blk  = blockIdx.x;
    const int row0 = blk * RPB;
    const int c0   = t * 4;
    const float* wl = w4 + LAY * DD;

    __shared__ float lds_z[8][8];
    __shared__ float lds_s[8];
    __shared__ float lds_t[RPB][4];
    __shared__ float lds_dote[8];

    float wr[4];
    *(float4*)&wr[0] = *(const float4*)(wl + c0);

    float u0[4], u1[4], u2[4], u3[4];
    if constexpr (LAY == 0) {
        #pragma unroll
        for (int i = 0; i < 4; ++i) u0[i] = wr[i];
    } else {
        float a4[4]; *(float4*)&a4[0] = *(const float4*)(avec + c0);
        #pragma unroll
        for (int i = 0; i < 4; ++i) u0[i] = a4[i] * wr[i];
    }
    if constexpr (LAY >= 1) {
        float cc[4]; *(float4*)&cc[0] = *(const float4*)(cvec + 0 * DD + c0);
        #pragma unroll
        for (int i = 0; i < 4; ++i) u1[i] = cc[i] * wr[i];
    }
    if constexpr (LAY >= 2) {
        float cc[4]; *(float4*)&cc[0] = *(const float4*)(cvec + 1 * DD + c0);
        #pragma unroll
        for (int i = 0; i < 4; ++i) u2[i] = cc[i] * wr[i];
    }
    if constexpr (LAY >= 3) {
        float cc[4]; *(float4*)&cc[0] = *(const float4*)(cvec + 2 * DD + c0);
        #pragma unroll
        for (int i = 0; i < 4; ++i) u3[i] = cc[i] * wr[i];
    }

    if constexpr (LAY >= 1) {
        if (t < RPB) {
            lds_t[t][0] = tbuf[0 * BB + row0 + t];
            if constexpr (LAY >= 2) lds_t[t][1] = tbuf[1 * BB + row0 + t];
            if constexpr (LAY >= 3) lds_t[t][2] = tbuf[2 * BB + row0 + t];
        }
    }

    float dote = 0.f;
    if constexpr (LAY > 0) {
        float e4[4]; *(float4*)&e4[0] = *(const float4*)(evec + c0);
        float p = e4[0] * wr[0] + e4[1] * wr[1] + e4[2] * wr[2] + e4[3] * wr[3];
        #pragma unroll
        for (int off = 32; off; off >>= 1) p += __shfl_xor(p, off, 64);
        if (lane == 0) lds_dote[wv] = p;
        __syncthreads();   // also publishes lds_t
        dote = lds_dote[0] + lds_dote[1] + lds_dote[2] + lds_dote[3]
             + lds_dote[4] + lds_dote[5] + lds_dote[6] + lds_dote[7];
    }

    float pa_m1[4] = {0, 0, 0, 0};
    float pa_20[4] = {0, 0, 0, 0};
    float pa_j1[4] = {0, 0, 0, 0};
    float pa_j2[4] = {0, 0, 0, 0};
    float pa_j3[4] = {0, 0, 0, 0};
    float pa_nn[4] = {0, 0, 0, 0};
    float pa_X1[4] = {0, 0, 0, 0};
    float pa_X2[4] = {0, 0, 0, 0};

    #pragma unroll
    for (int g = 0; g < RPB / 8; ++g) {
        float xr[8][4];
        float cp[8];
        #pragma unroll
        for (int rr = 0; rr < 8; ++rr) {
            const int row = row0 + g * 8 + rr;
            *(float4*)&xr[rr][0] = *(const float4*)(x + (size_t)row * DD + c0);
            float we[4];
            #pragma unroll
            for (int i = 0; i < 4; ++i) we[i] = u0[i];
            if constexpr (LAY >= 1) {
                const float t1 = lds_t[g * 8 + rr][0];
                #pragma unroll
                for (int i = 0; i < 4; ++i) we[i] = fmaf(t1, u1[i], we[i]);
            }
            if constexpr (LAY >= 2) {
                const float t2 = lds_t[g * 8 + rr][1];
                #pragma unroll
                for (int i = 0; i < 4; ++i) we[i] = fmaf(t2, u2[i], we[i]);
            }
            if constexpr (LAY >= 3) {
                const float t3 = lds_t[g * 8 + rr][2];
                #pragma unroll
                for (int i = 0; i < 4; ++i) we[i] = fmaf(t3, u3[i], we[i]);
            }
            float a = xr[rr][0] * we[0];
            a = fmaf(xr[rr][1], we[1], a);
            a = fmaf(xr[rr][2], we[2], a);
            a = fmaf(xr[rr][3], we[3], a);
            cp[rr] = a;
        }
        #pragma unroll
        for (int off = 32; off; off >>= 1) {
            #pragma unroll
            for (int rr = 0; rr < 8; ++rr)
                cp[rr] += __shfl_xor(cp[rr], off, 64);
        }
        if (lane == 0) {
            #pragma unroll
            for (int rr = 0; rr < 8; ++rr) lds_z[wv][rr] = cp[rr];
        }
        __syncthreads();
        if (t < 8) {
            const int row = row0 + g * 8 + t;
            float s = dote;
            #pragma unroll
            for (int w = 0; w < 8; ++w) s += lds_z[w][t];
            tbuf[LAY * BB + row] = s;
            lds_s[t] = s;
        }
        __syncthreads();
        #pragma unroll
        for (int rr = 0; rr < 8; ++rr) {
            const float s = lds_s[rr];
            #pragma unroll
            for (int i = 0; i < 4; ++i) {
                const float xa = xr[rr][i];
                const float x2 = xa * xa;
                const float xs2 = x2 * s;
                pa_m1[i] = fmaf(xa, s, pa_m1[i]);
                pa_20[i] += xs2;
                if constexpr (LAY >= 1) pa_j1[i] = fmaf(xs2, lds_t[g * 8 + rr][0], pa_j1[i]);
                if constexpr (LAY >= 2) pa_j2[i] = fmaf(xs2, lds_t[g * 8 + rr][1], pa_j2[i]);
                if constexpr (LAY >= 3) pa_j3[i] = fmaf(xs2, lds_t[g * 8 + rr][2], pa_j3[i]);
                pa_nn[i] = fmaf(xs2, s, pa_nn[i]);
                if constexpr (LAY == 0) {
                    pa_X1[i] += xa;
                    pa_X2[i] += x2;
                }
            }
        }
    }

    float* pp = partials + (size_t)blk * NV * DD + c0;
    *(float4*)(pp + 0 * DD) = *(float4*)&pa_m1[0];
    *(float4*)(pp + 1 * DD) = *(float4*)&pa_20[0];
    if constexpr (LAY == 0) {
        *(float4*)(pp + 2 * DD) = *(float4*)&pa_nn[0];
        *(float4*)(pp + 3 * DD) = *(float4*)&pa_X1[0];
        *(float4*)(pp + 4 * DD) = *(float4*)&pa_X2[0];
    } else {
        if constexpr (LAY >= 1) *(float4*)(pp + 2 * DD) = *(float4*)&pa_j1[0];
        if constexpr (LAY >= 2) *(float4*)(pp + 3 * DD) = *(float4*)&pa_j2[0];
        if constexpr (LAY >= 3) *(float4*)(pp + 4 * DD) = *(float4*)&pa_j3[0];
        *(float4*)(pp + (2 + LAY) * DD) = *(float4*)&pa_nn[0];
    }
}

// Fused reduce + stats: stage A identical to r16's k_red_a; last-8-ticket
// blocks spin (device-scope RMW, XCD-coherent) then run the r16-verified
// stats algebra on a 256-column slice each. Deadlock-free unconditionally:
// spinners exist only once >= total-8 blocks completed.
template <int LAY>
__global__ __launch_bounds__(256) void k_redstat(
    float* __restrict__ ws, const float* __restrict__ b4, unsigned* __restrict__ counter)
{
    constexpr int NV = (LAY == 0) ? 5 : (3 + LAY);
    constexpr int NCH = NV * 8;
    constexpr unsigned TOTAL = 16 * NCH;
    constexpr int L = LAY + 1;

    // ---- stage A: partials[NB][nv*DD] -> mid[16][nv*DD]
    {
        const int pg = blockIdx.x / NCH;
        const int ec = blockIdx.x - pg * NCH;
        const int e  = ec * 256 + threadIdx.x;
        const float* partials = ws + OFF_P;
        float* mid = ws + OFF_MID;
        const int p0 = pg * (NB / 16);
        float acc = 0.f;
        #pragma unroll 4
        for (int p = 0; p < NB / 16; ++p)
            acc += partials[(size_t)(p0 + p) * NV * DD + e];
        mid[(size_t)pg * NV * DD + e] = acc;
    }
    __threadfence();

    __shared__ unsigned ticket;
    if (threadIdx.x == 0) ticket = atomicAdd(counter, 1u);
    __syncthreads();
    if (ticket < TOTAL - 8) return;

    if (threadIdx.x == 0) {
        while (atomicAdd(counter, 0u) < TOTAL) { }
    }
    __syncthreads();
    __threadfence();

    // ---- stage B: stats for columns [slice*256, slice*256+256)
    const int slice = (int)(TOTAL - 1 - ticket);   // 0..7
    const int d = slice * 256 + threadIdx.x;

    float* M1 = ws + OFF_M1;
    float* M2 = ws + OFF_M2;
    const float* mid = ws + OFF_MID;
    float* a = ws + OFF_A;
    float* c = ws + OFF_C;
    float* e = ws + OFF_E;
    const float invB = 1.f / (float)BB;

    float Mn[NV];
    #pragma unroll
    for (int v = 0; v < NV; ++v) {
        float acc = 0.f;
        #pragma unroll
        for (int pg = 0; pg < 16; ++pg)
            acc += mid[(size_t)pg * NV * DD + v * DD + d];
        Mn[v] = acc;
    }

    float g[5], m1v[5], m2v[5][5];

    g[0] = (LAY == 0) ? 1.f : a[d];
    #pragma unroll
    for (int k = 1; k <= LAY; ++k) g[k] = c[(k - 1) * DD + d];
    g[L] = 1.f;

    if constexpr (LAY == 0) m1v[0] = Mn[3];
    else                    m1v[0] = M1[0 * DD + d];
    #pragma unroll
    for (int k = 1; k <= LAY; ++k) m1v[k] = M1[k * DD + d];
    m1v[L] = Mn[0];

    if constexpr (LAY == 0) {
        m2v[0][0] = Mn[4];
    } else {
        #pragma unroll
        for (int k = 0; k <= LAY; ++k)
            #pragma unroll
            for (int j = 0; j <= LAY; ++j)
                if (j <= k) m2v[j][k] = M2[P2(j, k) * DD + d];
    }
    m2v[0][L] = Mn[1];
    #pragma unroll
    for (int j = 1; j <= LAY; ++j) m2v[j][L] = Mn[1 + j];
    m2v[L][L] = Mn[2 + LAY];

    // persist new moments
    M1[L * DD + d]         = m1v[L];
    M2[P2(0, L) * DD + d]  = m2v[0][L];
    #pragma unroll
    for (int j = 1; j <= LAY; ++j) M2[P2(j, L) * DD + d] = m2v[j][L];
    M2[P2(L, L) * DD + d]  = m2v[L][L];
    if constexpr (LAY == 0) { M1[0 * DD + d] = m1v[0]; M2[0 * DD + d] = m2v[0][0]; }

    // stats
    const float E = ((LAY == 0) ? 0.f : e[d]) + b4[LAY * DD + d];
    float mxG = 0.f;
    #pragma unroll
    for (int k = 0; k <= L; ++k) mxG += g[k] * m1v[k];
    mxG *= invB;
    const float mu = mxG + E;
    float ex2 = 0.f;
    #pragma unroll
    for (int k = 0; k <= L; ++k) {
        ex2 += g[k] * g[k] * m2v[k][k];
        #pragma unroll
        for (int j = 0; j <= L; ++j)
            if (j < k) ex2 += 2.f * g[j] * g[k] * m2v[j][k];
    }
    ex2 *= invB;
    const float second = ex2 + 2.f * E * mxG + E * E;
    const float var = fmaxf(second - mu * mu, 0.f);
    const float inv = rsqrtf(var + BN_EPS);

    a[d] = g[0] * inv;
    #pragma unroll
    for (int k = 1; k <= LAY; ++k) c[(k - 1) * DD + d] = g[k] * inv;
    c[(L - 1) * DD + d] = inv;
    e[d] = (E - mu) * inv;
}

// out[b,d] = x[b,d]*(a[d] + sum_k c_k[d]*t_k[b]) + e[d]
__global__ __launch_bounds__(256) void k_final(
    const float* __restrict__ x, const float* __restrict__ ws, float* __restrict__ out)
{
    const int t = threadIdx.x;
    const int blk = blockIdx.x;
    const int row0 = blk * 8;
    const int c0 = t * 8;
    const float* a = ws + OFF_A;
    const float* c = ws + OFF_C;
    const float* e = ws + OFF_E;
    const float* tbuf = ws + OFF_T;

    __shared__ float lt[4][8];
    if (t < 32) lt[t >> 3][t & 7] = tbuf[(t >> 3) * BB + row0 + (t & 7)];
    __syncthreads();

    float a8[8], e8[8], c8[4][8];
    *(float4*)&a8[0] = *(const float4*)(a + c0);
    *(float4*)&a8[4] = *(const float4*)(a + c0 + 4);
    *(float4*)&e8[0] = *(const float4*)(e + c0);
    *(float4*)&e8[4] = *(const float4*)(e + c0 + 4);
    #pragma unroll
    for (int k = 0; k < 4; ++k) {
        *(float4*)&c8[k][0] = *(const float4*)(c + k * DD + c0);
        *(float4*)&c8[k][4] = *(const float4*)(c + k * DD + c0 + 4);
    }
    #pragma unroll
    for (int r = 0; r < 8; ++r) {
        const size_t base = (size_t)(row0 + r) * DD + c0;
        float xv[8], o[8];
        *(float4*)&xv[0] = *(const float4*)(x + base);
        *(float4*)&xv[4] = *(const float4*)(x + base + 4);
        const float t0 = lt[0][r], t1 = lt[1][r], t2 = lt[2][r], t3 = lt[3][r];
        #pragma unroll
        for (int i = 0; i < 8; ++i) {
            float gg = a8[i];
            gg = fmaf(c8[0][i], t0, gg);
            gg = fmaf(c8[1][i], t1, gg);
            gg = fmaf(c8[2][i], t2, gg);
            gg = fmaf(c8[3][i], t3, gg);
            o[i] = fmaf(xv[i], gg, e8[i]);
        }
        *(float4*)(out + base)     = *(float4*)&o[0];
        *(float4*)(out + base + 4) = *(float4*)&o[4];
    }
}

extern "C" void kernel_launch(void* const* d_in, const int* in_sizes, int n_in,
                              void* d_out, int out_size, void* d_ws, size_t ws_size,
                              hipStream_t stream) {
    const float* x  = (const float*)d_in[0];   // [B, D]
    const float* w  = (const float*)d_in[1];   // [4, D]
    const float* bb = (const float*)d_in[2];   // [4, D]
    float* out = (float*)d_out;
    float* ws  = (float*)d_ws;
    unsigned* cnt = (unsigned*)(ws + OFF_CNT);

    hipMemsetAsync(cnt, 0, 4 * sizeof(unsigned), stream);

    k_pass<0><<<NB, PASS_THR, 0, stream>>>(x, w, ws);
    k_redstat<0><<<16 * 5 * 8, 256, 0, stream>>>(ws, bb, cnt + 0);

    k_pass<1><<<NB, PASS_THR, 0, stream>>>(x, w, ws);
    k_redstat<1><<<16 * 4 * 8, 256, 0, stream>>>(ws, bb, cnt + 1);

    k_pass<2><<<NB, PASS_THR, 0, stream>>>(x, w, ws);
    k_redstat<2><<<16 * 5 * 8, 256, 0, stream>>>(ws, bb, cnt + 2);

    k_pass<3><<<NB, PASS_THR, 0, stream>>>(x, w, ws);
    k_redstat<3><<<16 * 6 * 8, 256, 0, stream>>>(ws, bb, cnt + 3);

    k_final<<<BB / 8, 256, 0, stream>>>(x, ws, out);
}

// Round 18
// 165.074 us; speedup vs baseline: 1.9506x; 1.9506x over previous
//
#include <hip/hip_runtime.h>
#include <math.h>

#define BB 8192
#define DD 2048
#define BN_EPS 1e-5f
#define NB 256          // pass blocks (r17: 512->256 halves partials traffic)
#define RPB 32          // rows per pass block
#define PASS_THR 512

// ws layout (floats)
#define OFF_T  0                    // tbuf[4][BB]   (t_k = s_{k-1})
#define OFF_A  (4 * BB)             // a[DD]
#define OFF_C  (OFF_A + DD)         // c[4][DD]
#define OFF_E  (OFF_C + 4 * DD)     // e[DD]
#define OFF_M1 (OFF_E + DD)         // M1[5][DD]
#define OFF_M2 (OFF_M1 + 5 * DD)    // M2[15][DD]
#define OFF_MID (OFF_M2 + 15 * DD)  // mid[16][6][DD]
#define OFF_P  (OFF_MID + 16 * 6 * DD) // partials[NB][nv][DD]

__host__ __device__ constexpr int P2(int j, int k) { return k * (k + 1) / 2 + j; }

// One pass over x per layer (r16-verified: fold t-combination before the
// butterfly -> ONE shfl reduction per row). r17 lesson: do NOT fuse the
// reduce+stats with an intra-kernel spin barrier — ~68us/kernel stall on
// MI355X (cross-XCD atomic polling); separate launches cost only ~2us each.
template <int LAY>
__global__ __launch_bounds__(PASS_THR) void k_pass(
    const float* __restrict__ x, const float* __restrict__ w4, float* __restrict__ ws)
{
    constexpr int NV = (LAY == 0) ? 5 : (3 + LAY);
    const float* avec = ws + OFF_A;
    const float* cvec = ws + OFF_C;
    const float* evec = ws + OFF_E;
    float* tbuf     = ws + OFF_T;
    float* partials = ws + OFF_P;

    const int t    = threadIdx.x;
    const int lane = t & 63;
    const int wv   = t >> 6;            // 8 waves
    const int blk  = blockIdx.x;
    const int row0 = blk * RPB;
    const int c0   = t * 4;
    const float* wl = w4 + LAY * DD;

    __shared__ float lds_z[8][8];
    __shared__ float lds_s[8];
    __shared__ float lds_t[RPB][4];
    __shared__ float lds_dote[8];

    float wr[4];
    *(float4*)&wr[0] = *(const float4*)(wl + c0);

    float u0[4], u1[4], u2[4], u3[4];
    if constexpr (LAY == 0) {
        #pragma unroll
        for (int i = 0; i < 4; ++i) u0[i] = wr[i];
    } else {
        float a4[4]; *(float4*)&a4[0] = *(const float4*)(avec + c0);
        #pragma unroll
        for (int i = 0; i < 4; ++i) u0[i] = a4[i] * wr[i];
    }
    if constexpr (LAY >= 1) {
        float cc[4]; *(float4*)&cc[0] = *(const float4*)(cvec + 0 * DD + c0);
        #pragma unroll
        for (int i = 0; i < 4; ++i) u1[i] = cc[i] * wr[i];
    }
    if constexpr (LAY >= 2) {
        float cc[4]; *(float4*)&cc[0] = *(const float4*)(cvec + 1 * DD + c0);
        #pragma unroll
        for (int i = 0; i < 4; ++i) u2[i] = cc[i] * wr[i];
    }
    if constexpr (LAY >= 3) {
        float cc[4]; *(float4*)&cc[0] = *(const float4*)(cvec + 2 * DD + c0);
        #pragma unroll
        for (int i = 0; i < 4; ++i) u3[i] = cc[i] * wr[i];
    }

    if constexpr (LAY >= 1) {
        if (t < RPB) {
            lds_t[t][0] = tbuf[0 * BB + row0 + t];
            if constexpr (LAY >= 2) lds_t[t][1] = tbuf[1 * BB + row0 + t];
            if constexpr (LAY >= 3) lds_t[t][2] = tbuf[2 * BB + row0 + t];
        }
    }

    float dote = 0.f;
    if constexpr (LAY > 0) {
        float e4[4]; *(float4*)&e4[0] = *(const float4*)(evec + c0);
        float p = e4[0] * wr[0] + e4[1] * wr[1] + e4[2] * wr[2] + e4[3] * wr[3];
        #pragma unroll
        for (int off = 32; off; off >>= 1) p += __shfl_xor(p, off, 64);
        if (lane == 0) lds_dote[wv] = p;
        __syncthreads();   // also publishes lds_t
        dote = lds_dote[0] + lds_dote[1] + lds_dote[2] + lds_dote[3]
             + lds_dote[4] + lds_dote[5] + lds_dote[6] + lds_dote[7];
    } else {
        __syncthreads();
    }

    float pa_m1[4] = {0, 0, 0, 0};
    float pa_20[4] = {0, 0, 0, 0};
    float pa_j1[4] = {0, 0, 0, 0};
    float pa_j2[4] = {0, 0, 0, 0};
    float pa_j3[4] = {0, 0, 0, 0};
    float pa_nn[4] = {0, 0, 0, 0};
    float pa_X1[4] = {0, 0, 0, 0};
    float pa_X2[4] = {0, 0, 0, 0};

    #pragma unroll
    for (int g = 0; g < RPB / 8; ++g) {
        float xr[8][4];
        float cp[8];
        #pragma unroll
        for (int rr = 0; rr < 8; ++rr) {
            const int row = row0 + g * 8 + rr;
            *(float4*)&xr[rr][0] = *(const float4*)(x + (size_t)row * DD + c0);
            float we[4];
            #pragma unroll
            for (int i = 0; i < 4; ++i) we[i] = u0[i];
            if constexpr (LAY >= 1) {
                const float t1 = lds_t[g * 8 + rr][0];
                #pragma unroll
                for (int i = 0; i < 4; ++i) we[i] = fmaf(t1, u1[i], we[i]);
            }
            if constexpr (LAY >= 2) {
                const float t2 = lds_t[g * 8 + rr][1];
                #pragma unroll
                for (int i = 0; i < 4; ++i) we[i] = fmaf(t2, u2[i], we[i]);
            }
            if constexpr (LAY >= 3) {
                const float t3 = lds_t[g * 8 + rr][2];
                #pragma unroll
                for (int i = 0; i < 4; ++i) we[i] = fmaf(t3, u3[i], we[i]);
            }
            float a = xr[rr][0] * we[0];
            a = fmaf(xr[rr][1], we[1], a);
            a = fmaf(xr[rr][2], we[2], a);
            a = fmaf(xr[rr][3], we[3], a);
            cp[rr] = a;
        }
        #pragma unroll
        for (int off = 32; off; off >>= 1) {
            #pragma unroll
            for (int rr = 0; rr < 8; ++rr)
                cp[rr] += __shfl_xor(cp[rr], off, 64);
        }
        if (lane == 0) {
            #pragma unroll
            for (int rr = 0; rr < 8; ++rr) lds_z[wv][rr] = cp[rr];
        }
        __syncthreads();
        if (t < 8) {
            const int row = row0 + g * 8 + t;
            float s = dote;
            #pragma unroll
            for (int w = 0; w < 8; ++w) s += lds_z[w][t];
            tbuf[LAY * BB + row] = s;
            lds_s[t] = s;
        }
        __syncthreads();
        #pragma unroll
        for (int rr = 0; rr < 8; ++rr) {
            const float s = lds_s[rr];
            #pragma unroll
            for (int i = 0; i < 4; ++i) {
                const float xa = xr[rr][i];
                const float x2 = xa * xa;
                const float xs2 = x2 * s;
                pa_m1[i] = fmaf(xa, s, pa_m1[i]);
                pa_20[i] += xs2;
                if constexpr (LAY >= 1) pa_j1[i] = fmaf(xs2, lds_t[g * 8 + rr][0], pa_j1[i]);
                if constexpr (LAY >= 2) pa_j2[i] = fmaf(xs2, lds_t[g * 8 + rr][1], pa_j2[i]);
                if constexpr (LAY >= 3) pa_j3[i] = fmaf(xs2, lds_t[g * 8 + rr][2], pa_j3[i]);
                pa_nn[i] = fmaf(xs2, s, pa_nn[i]);
                if constexpr (LAY == 0) {
                    pa_X1[i] += xa;
                    pa_X2[i] += x2;
                }
            }
        }
    }

    float* pp = partials + (size_t)blk * NV * DD + c0;
    *(float4*)(pp + 0 * DD) = *(float4*)&pa_m1[0];
    *(float4*)(pp + 1 * DD) = *(float4*)&pa_20[0];
    if constexpr (LAY == 0) {
        *(float4*)(pp + 2 * DD) = *(float4*)&pa_nn[0];
        *(float4*)(pp + 3 * DD) = *(float4*)&pa_X1[0];
        *(float4*)(pp + 4 * DD) = *(float4*)&pa_X2[0];
    } else {
        if constexpr (LAY >= 1) *(float4*)(pp + 2 * DD) = *(float4*)&pa_j1[0];
        if constexpr (LAY >= 2) *(float4*)(pp + 3 * DD) = *(float4*)&pa_j2[0];
        if constexpr (LAY >= 3) *(float4*)(pp + 4 * DD) = *(float4*)&pa_j3[0];
        *(float4*)(pp + (2 + LAY) * DD) = *(float4*)&pa_nn[0];
    }
}

// Stage A: partials[NB][nv*DD] -> mid[16][nv*DD]
__global__ __launch_bounds__(256) void k_red_a(
    const float* __restrict__ partials, float* __restrict__ mid,
    int nv, int nchunks)
{
    const int pg = blockIdx.x / nchunks;
    const int ec = blockIdx.x - pg * nchunks;
    const int e  = ec * 256 + threadIdx.x;        // e < nv*DD
    const int p0 = pg * (NB / 16);
    float acc = 0.f;
    #pragma unroll 4
    for (int p = 0; p < NB / 16; ++p)
        acc += partials[(size_t)(p0 + p) * nv * DD + e];
    mid[(size_t)pg * nv * DD + e] = acc;
}

// Stage B folded into stats: reduce 16 mids per moment, then the layer algebra.
template <int LAY>
__global__ __launch_bounds__(256) void k_stats(float* __restrict__ ws,
                                               const float* __restrict__ b4)
{
    constexpr int NV = (LAY == 0) ? 5 : (3 + LAY);
    const int d = blockIdx.x * 256 + threadIdx.x;
    constexpr int L = LAY + 1;
    float* M1 = ws + OFF_M1;
    float* M2 = ws + OFF_M2;
    const float* mid = ws + OFF_MID;
    float* a = ws + OFF_A;
    float* c = ws + OFF_C;
    float* e = ws + OFF_E;
    const float invB = 1.f / (float)BB;

    float Mn[NV];
    #pragma unroll
    for (int v = 0; v < NV; ++v) {
        float acc = 0.f;
        #pragma unroll
        for (int pg = 0; pg < 16; ++pg)
            acc += mid[(size_t)pg * NV * DD + v * DD + d];
        Mn[v] = acc;
    }

    float g[5], m1v[5], m2v[5][5];

    g[0] = (LAY == 0) ? 1.f : a[d];
    #pragma unroll
    for (int k = 1; k <= LAY; ++k) g[k] = c[(k - 1) * DD + d];
    g[L] = 1.f;

    if constexpr (LAY == 0) m1v[0] = Mn[3];
    else                    m1v[0] = M1[0 * DD + d];
    #pragma unroll
    for (int k = 1; k <= LAY; ++k) m1v[k] = M1[k * DD + d];
    m1v[L] = Mn[0];

    if constexpr (LAY == 0) {
        m2v[0][0] = Mn[4];
    } else {
        #pragma unroll
        for (int k = 0; k <= LAY; ++k)
            #pragma unroll
            for (int j = 0; j <= LAY; ++j)
                if (j <= k) m2v[j][k] = M2[P2(j, k) * DD + d];
    }
    m2v[0][L] = Mn[1];
    #pragma unroll
    for (int j = 1; j <= LAY; ++j) m2v[j][L] = Mn[1 + j];
    m2v[L][L] = Mn[2 + LAY];

    // persist new moments
    M1[L * DD + d]         = m1v[L];
    M2[P2(0, L) * DD + d]  = m2v[0][L];
    #pragma unroll
    for (int j = 1; j <= LAY; ++j) M2[P2(j, L) * DD + d] = m2v[j][L];
    M2[P2(L, L) * DD + d]  = m2v[L][L];
    if constexpr (LAY == 0) { M1[0 * DD + d] = m1v[0]; M2[0 * DD + d] = m2v[0][0]; }

    // stats
    const float E = ((LAY == 0) ? 0.f : e[d]) + b4[LAY * DD + d];
    float mxG = 0.f;
    #pragma unroll
    for (int k = 0; k <= L; ++k) mxG += g[k] * m1v[k];
    mxG *= invB;
    const float mu = mxG + E;
    float ex2 = 0.f;
    #pragma unroll
    for (int k = 0; k <= L; ++k) {
        ex2 += g[k] * g[k] * m2v[k][k];
        #pragma unroll
        for (int j = 0; j <= L; ++j)
            if (j < k) ex2 += 2.f * g[j] * g[k] * m2v[j][k];
    }
    ex2 *= invB;
    const float second = ex2 + 2.f * E * mxG + E * E;
    const float var = fmaxf(second - mu * mu, 0.f);
    const float inv = rsqrtf(var + BN_EPS);

    a[d] = g[0] * inv;
    #pragma unroll
    for (int k = 1; k <= LAY; ++k) c[(k - 1) * DD + d] = g[k] * inv;
    c[(L - 1) * DD + d] = inv;
    e[d] = (E - mu) * inv;
}

// out[b,d] = x[b,d]*(a[d] + sum_k c_k[d]*t_k[b]) + e[d]
__global__ __launch_bounds__(256) void k_final(
    const float* __restrict__ x, const float* __restrict__ ws, float* __restrict__ out)
{
    const int t = threadIdx.x;
    const int blk = blockIdx.x;
    const int row0 = blk * 8;
    const int c0 = t * 8;
    const float* a = ws + OFF_A;
    const float* c = ws + OFF_C;
    const float* e = ws + OFF_E;
    const float* tbuf = ws + OFF_T;

    __shared__ float lt[4][8];
    if (t < 32) lt[t >> 3][t & 7] = tbuf[(t >> 3) * BB + row0 + (t & 7)];
    __syncthreads();

    float a8[8], e8[8], c8[4][8];
    *(float4*)&a8[0] = *(const float4*)(a + c0);
    *(float4*)&a8[4] = *(const float4*)(a + c0 + 4);
    *(float4*)&e8[0] = *(const float4*)(e + c0);
    *(float4*)&e8[4] = *(const float4*)(e + c0 + 4);
    #pragma unroll
    for (int k = 0; k < 4; ++k) {
        *(float4*)&c8[k][0] = *(const float4*)(c + k * DD + c0);
        *(float4*)&c8[k][4] = *(const float4*)(c + k * DD + c0 + 4);
    }
    #pragma unroll
    for (int r = 0; r < 8; ++r) {
        const size_t base = (size_t)(row0 + r) * DD + c0;
        float xv[8], o[8];
        *(float4*)&xv[0] = *(const float4*)(x + base);
        *(float4*)&xv[4] = *(const float4*)(x + base + 4);
        const float t0 = lt[0][r], t1 = lt[1][r], t2 = lt[2][r], t3 = lt[3][r];
        #pragma unroll
        for (int i = 0; i < 8; ++i) {
            float gg = a8[i];
            gg = fmaf(c8[0][i], t0, gg);
            gg = fmaf(c8[1][i], t1, gg);
            gg = fmaf(c8[2][i], t2, gg);
            gg = fmaf(c8[3][i], t3, gg);
            o[i] = fmaf(xv[i], gg, e8[i]);
        }
        *(float4*)(out + base)     = *(float4*)&o[0];
        *(float4*)(out + base + 4) = *(float4*)&o[4];
    }
}

extern "C" void kernel_launch(void* const* d_in, const int* in_sizes, int n_in,
                              void* d_out, int out_size, void* d_ws, size_t ws_size,
                              hipStream_t stream) {
    const float* x  = (const float*)d_in[0];   // [B, D]
    const float* w  = (const float*)d_in[1];   // [4, D]
    const float* bb = (const float*)d_in[2];   // [4, D]
    float* out = (float*)d_out;
    float* ws  = (float*)d_ws;
    float* partials = ws + OFF_P;
    float* mid      = ws + OFF_MID;

    k_pass<0><<<NB, PASS_THR, 0, stream>>>(x, w, ws);
    k_red_a<<<16 * 5 * 8, 256, 0, stream>>>(partials, mid, 5, 5 * 8);
    k_stats<0><<<8, 256, 0, stream>>>(ws, bb);

    k_pass<1><<<NB, PASS_THR, 0, stream>>>(x, w, ws);
    k_red_a<<<16 * 4 * 8, 256, 0, stream>>>(partials, mid, 4, 4 * 8);
    k_stats<1><<<8, 256, 0, stream>>>(ws, bb);

    k_pass<2><<<NB, PASS_THR, 0, stream>>>(x, w, ws);
    k_red_a<<<16 * 5 * 8, 256, 0, stream>>>(partials, mid, 5, 5 * 8);
    k_stats<2><<<8, 256, 0, stream>>>(ws, bb);

    k_pass<3><<<NB, PASS_THR, 0, stream>>>(x, w, ws);
    k_red_a<<<16 * 6 * 8, 256, 0, stream>>>(partials, mid, 6, 6 * 8);
    k_stats<3><<<8, 256, 0, stream>>>(ws, bb);

    k_final<<<BB / 8, 256, 0, stream>>>(x, ws, out);
}

// Round 19
// 134.678 us; speedup vs baseline: 2.3909x; 1.2257x over previous
//
#include <hip/hip_runtime.h>
#include <math.h>

#define BB 8192
#define DD 2048
#define BN_EPS 1e-5f
#define NB 512          // pass blocks — MUST be >= 2 blocks/CU (r18: 256 -> 1
                        // block/CU -> latency-bound 50us/pass; 512 -> 13us)
#define RPB 16          // rows per pass block
#define PASS_THR 512

// ws layout (floats)
#define OFF_T  0                    // tbuf[4][BB]   (t_k = s_{k-1})
#define OFF_A  (4 * BB)             // a[DD]
#define OFF_C  (OFF_A + DD)         // c[4][DD]
#define OFF_E  (OFF_C + 4 * DD)     // e[DD]
#define OFF_M1 (OFF_E + DD)         // M1[5][DD]
#define OFF_M2 (OFF_M1 + 5 * DD)    // M2[15][DD]
#define OFF_MID (OFF_M2 + 15 * DD)  // mid[16][6][DD]
#define OFF_P  (OFF_MID + 16 * 6 * DD) // partials[NB][nv][DD]

__host__ __device__ constexpr int P2(int j, int k) { return k * (k + 1) / 2 + j; }

// One pass over x per layer (r16-verified @134us: fold t-combination before
// the butterfly -> ONE shfl reduction per row). Ledger: r17 spin-fusion =
// ~68us/kernel stall (cross-XCD atomic polling) -> keep separate launches;
// r18 NB=256 = 1 block/CU latency cliff -> keep NB=512.
template <int LAY>
__global__ __launch_bounds__(PASS_THR) void k_pass(
    const float* __restrict__ x, const float* __restrict__ w4, float* __restrict__ ws)
{
    constexpr int NV = (LAY == 0) ? 5 : (3 + LAY);
    const float* avec = ws + OFF_A;
    const float* cvec = ws + OFF_C;
    const float* evec = ws + OFF_E;
    float* tbuf     = ws + OFF_T;
    float* partials = ws + OFF_P;

    const int t    = threadIdx.x;
    const int lane = t & 63;
    const int wv   = t >> 6;            // 8 waves
    const int blk  = blockIdx.x;
    const int row0 = blk * RPB;
    const int c0   = t * 4;
    const float* wl = w4 + LAY * DD;

    __shared__ float lds_z[8][8];
    __shared__ float lds_s[8];
    __shared__ float lds_t[RPB][4];
    __shared__ float lds_dote[8];

    float wr[4];
    *(float4*)&wr[0] = *(const float4*)(wl + c0);

    float u0[4], u1[4], u2[4], u3[4];
    if constexpr (LAY == 0) {
        #pragma unroll
        for (int i = 0; i < 4; ++i) u0[i] = wr[i];
    } else {
        float a4[4]; *(float4*)&a4[0] = *(const float4*)(avec + c0);
        #pragma unroll
        for (int i = 0; i < 4; ++i) u0[i] = a4[i] * wr[i];
    }
    if constexpr (LAY >= 1) {
        float cc[4]; *(float4*)&cc[0] = *(const float4*)(cvec + 0 * DD + c0);
        #pragma unroll
        for (int i = 0; i < 4; ++i) u1[i] = cc[i] * wr[i];
    }
    if constexpr (LAY >= 2) {
        float cc[4]; *(float4*)&cc[0] = *(const float4*)(cvec + 1 * DD + c0);
        #pragma unroll
        for (int i = 0; i < 4; ++i) u2[i] = cc[i] * wr[i];
    }
    if constexpr (LAY >= 3) {
        float cc[4]; *(float4*)&cc[0] = *(const float4*)(cvec + 2 * DD + c0);
        #pragma unroll
        for (int i = 0; i < 4; ++i) u3[i] = cc[i] * wr[i];
    }

    if constexpr (LAY >= 1) {
        if (t < RPB) {
            lds_t[t][0] = tbuf[0 * BB + row0 + t];
            if constexpr (LAY >= 2) lds_t[t][1] = tbuf[1 * BB + row0 + t];
            if constexpr (LAY >= 3) lds_t[t][2] = tbuf[2 * BB + row0 + t];
        }
    }

    float dote = 0.f;
    if constexpr (LAY > 0) {
        float e4[4]; *(float4*)&e4[0] = *(const float4*)(evec + c0);
        float p = e4[0] * wr[0] + e4[1] * wr[1] + e4[2] * wr[2] + e4[3] * wr[3];
        #pragma unroll
        for (int off = 32; off; off >>= 1) p += __shfl_xor(p, off, 64);
        if (lane == 0) lds_dote[wv] = p;
        __syncthreads();   // also publishes lds_t
        dote = lds_dote[0] + lds_dote[1] + lds_dote[2] + lds_dote[3]
             + lds_dote[4] + lds_dote[5] + lds_dote[6] + lds_dote[7];
    }

    float pa_m1[4] = {0, 0, 0, 0};
    float pa_20[4] = {0, 0, 0, 0};
    float pa_j1[4] = {0, 0, 0, 0};
    float pa_j2[4] = {0, 0, 0, 0};
    float pa_j3[4] = {0, 0, 0, 0};
    float pa_nn[4] = {0, 0, 0, 0};
    float pa_X1[4] = {0, 0, 0, 0};
    float pa_X2[4] = {0, 0, 0, 0};

    #pragma unroll
    for (int g = 0; g < RPB / 8; ++g) {
        float xr[8][4];
        float cp[8];
        #pragma unroll
        for (int rr = 0; rr < 8; ++rr) {
            const int row = row0 + g * 8 + rr;
            *(float4*)&xr[rr][0] = *(const float4*)(x + (size_t)row * DD + c0);
            float we[4];
            #pragma unroll
            for (int i = 0; i < 4; ++i) we[i] = u0[i];
            if constexpr (LAY >= 1) {
                const float t1 = lds_t[g * 8 + rr][0];
                #pragma unroll
                for (int i = 0; i < 4; ++i) we[i] = fmaf(t1, u1[i], we[i]);
            }
            if constexpr (LAY >= 2) {
                const float t2 = lds_t[g * 8 + rr][1];
                #pragma unroll
                for (int i = 0; i < 4; ++i) we[i] = fmaf(t2, u2[i], we[i]);
            }
            if constexpr (LAY >= 3) {
                const float t3 = lds_t[g * 8 + rr][2];
                #pragma unroll
                for (int i = 0; i < 4; ++i) we[i] = fmaf(t3, u3[i], we[i]);
            }
            float a = xr[rr][0] * we[0];
            a = fmaf(xr[rr][1], we[1], a);
            a = fmaf(xr[rr][2], we[2], a);
            a = fmaf(xr[rr][3], we[3], a);
            cp[rr] = a;
        }
        #pragma unroll
        for (int off = 32; off; off >>= 1) {
            #pragma unroll
            for (int rr = 0; rr < 8; ++rr)
                cp[rr] += __shfl_xor(cp[rr], off, 64);
        }
        if (lane == 0) {
            #pragma unroll
            for (int rr = 0; rr < 8; ++rr) lds_z[wv][rr] = cp[rr];
        }
        __syncthreads();
        if (t < 8) {
            const int row = row0 + g * 8 + t;
            float s = dote;
            #pragma unroll
            for (int w = 0; w < 8; ++w) s += lds_z[w][t];
            tbuf[LAY * BB + row] = s;
            lds_s[t] = s;
        }
        __syncthreads();
        #pragma unroll
        for (int rr = 0; rr < 8; ++rr) {
            const float s = lds_s[rr];
            #pragma unroll
            for (int i = 0; i < 4; ++i) {
                const float xa = xr[rr][i];
                const float x2 = xa * xa;
                const float xs2 = x2 * s;
                pa_m1[i] = fmaf(xa, s, pa_m1[i]);
                pa_20[i] += xs2;
                if constexpr (LAY >= 1) pa_j1[i] = fmaf(xs2, lds_t[g * 8 + rr][0], pa_j1[i]);
                if constexpr (LAY >= 2) pa_j2[i] = fmaf(xs2, lds_t[g * 8 + rr][1], pa_j2[i]);
                if constexpr (LAY >= 3) pa_j3[i] = fmaf(xs2, lds_t[g * 8 + rr][2], pa_j3[i]);
                pa_nn[i] = fmaf(xs2, s, pa_nn[i]);
                if constexpr (LAY == 0) {
                    pa_X1[i] += xa;
                    pa_X2[i] += x2;
                }
            }
        }
    }

    float* pp = partials + (size_t)blk * NV * DD + c0;
    *(float4*)(pp + 0 * DD) = *(float4*)&pa_m1[0];
    *(float4*)(pp + 1 * DD) = *(float4*)&pa_20[0];
    if constexpr (LAY == 0) {
        *(float4*)(pp + 2 * DD) = *(float4*)&pa_nn[0];
        *(float4*)(pp + 3 * DD) = *(float4*)&pa_X1[0];
        *(float4*)(pp + 4 * DD) = *(float4*)&pa_X2[0];
    } else {
        if constexpr (LAY >= 1) *(float4*)(pp + 2 * DD) = *(float4*)&pa_j1[0];
        if constexpr (LAY >= 2) *(float4*)(pp + 3 * DD) = *(float4*)&pa_j2[0];
        if constexpr (LAY >= 3) *(float4*)(pp + 4 * DD) = *(float4*)&pa_j3[0];
        *(float4*)(pp + (2 + LAY) * DD) = *(float4*)&pa_nn[0];
    }
}

// Stage A: partials[NB][nv*DD] -> mid[16][nv*DD]
__global__ __launch_bounds__(256) void k_red_a(
    const float* __restrict__ partials, float* __restrict__ mid,
    int nv, int nchunks)
{
    const int pg = blockIdx.x / nchunks;
    const int ec = blockIdx.x - pg * nchunks;
    const int e  = ec * 256 + threadIdx.x;        // e < nv*DD
    const int p0 = pg * (NB / 16);
    float acc = 0.f;
    #pragma unroll 4
    for (int p = 0; p < NB / 16; ++p)
        acc += partials[(size_t)(p0 + p) * nv * DD + e];
    mid[(size_t)pg * nv * DD + e] = acc;
}

// Stage B folded into stats: reduce 16 mids per moment, then the layer algebra.
template <int LAY>
__global__ __launch_bounds__(256) void k_stats(float* __restrict__ ws,
                                               const float* __restrict__ b4)
{
    constexpr int NV = (LAY == 0) ? 5 : (3 + LAY);
    const int d = blockIdx.x * 256 + threadIdx.x;
    constexpr int L = LAY + 1;
    float* M1 = ws + OFF_M1;
    float* M2 = ws + OFF_M2;
    const float* mid = ws + OFF_MID;
    float* a = ws + OFF_A;
    float* c = ws + OFF_C;
    float* e = ws + OFF_E;
    const float invB = 1.f / (float)BB;

    float Mn[NV];
    #pragma unroll
    for (int v = 0; v < NV; ++v) {
        float acc = 0.f;
        #pragma unroll
        for (int pg = 0; pg < 16; ++pg)
            acc += mid[(size_t)pg * NV * DD + v * DD + d];
        Mn[v] = acc;
    }

    float g[5], m1v[5], m2v[5][5];

    g[0] = (LAY == 0) ? 1.f : a[d];
    #pragma unroll
    for (int k = 1; k <= LAY; ++k) g[k] = c[(k - 1) * DD + d];
    g[L] = 1.f;

    if constexpr (LAY == 0) m1v[0] = Mn[3];
    else                    m1v[0] = M1[0 * DD + d];
    #pragma unroll
    for (int k = 1; k <= LAY; ++k) m1v[k] = M1[k * DD + d];
    m1v[L] = Mn[0];

    if constexpr (LAY == 0) {
        m2v[0][0] = Mn[4];
    } else {
        #pragma unroll
        for (int k = 0; k <= LAY; ++k)
            #pragma unroll
            for (int j = 0; j <= LAY; ++j)
                if (j <= k) m2v[j][k] = M2[P2(j, k) * DD + d];
    }
    m2v[0][L] = Mn[1];
    #pragma unroll
    for (int j = 1; j <= LAY; ++j) m2v[j][L] = Mn[1 + j];
    m2v[L][L] = Mn[2 + LAY];

    // persist new moments
    M1[L * DD + d]         = m1v[L];
    M2[P2(0, L) * DD + d]  = m2v[0][L];
    #pragma unroll
    for (int j = 1; j <= LAY; ++j) M2[P2(j, L) * DD + d] = m2v[j][L];
    M2[P2(L, L) * DD + d]  = m2v[L][L];
    if constexpr (LAY == 0) { M1[0 * DD + d] = m1v[0]; M2[0 * DD + d] = m2v[0][0]; }

    // stats
    const float E = ((LAY == 0) ? 0.f : e[d]) + b4[LAY * DD + d];
    float mxG = 0.f;
    #pragma unroll
    for (int k = 0; k <= L; ++k) mxG += g[k] * m1v[k];
    mxG *= invB;
    const float mu = mxG + E;
    float ex2 = 0.f;
    #pragma unroll
    for (int k = 0; k <= L; ++k) {
        ex2 += g[k] * g[k] * m2v[k][k];
        #pragma unroll
        for (int j = 0; j <= L; ++j)
            if (j < k) ex2 += 2.f * g[j] * g[k] * m2v[j][k];
    }
    ex2 *= invB;
    const float second = ex2 + 2.f * E * mxG + E * E;
    const float var = fmaxf(second - mu * mu, 0.f);
    const float inv = rsqrtf(var + BN_EPS);

    a[d] = g[0] * inv;
    #pragma unroll
    for (int k = 1; k <= LAY; ++k) c[(k - 1) * DD + d] = g[k] * inv;
    c[(L - 1) * DD + d] = inv;
    e[d] = (E - mu) * inv;
}

// out[b,d] = x[b,d]*(a[d] + sum_k c_k[d]*t_k[b]) + e[d]
__global__ __launch_bounds__(256) void k_final(
    const float* __restrict__ x, const float* __restrict__ ws, float* __restrict__ out)
{
    const int t = threadIdx.x;
    const int blk = blockIdx.x;
    const int row0 = blk * 8;
    const int c0 = t * 8;
    const float* a = ws + OFF_A;
    const float* c = ws + OFF_C;
    const float* e = ws + OFF_E;
    const float* tbuf = ws + OFF_T;

    __shared__ float lt[4][8];
    if (t < 32) lt[t >> 3][t & 7] = tbuf[(t >> 3) * BB + row0 + (t & 7)];
    __syncthreads();

    float a8[8], e8[8], c8[4][8];
    *(float4*)&a8[0] = *(const float4*)(a + c0);
    *(float4*)&a8[4] = *(const float4*)(a + c0 + 4);
    *(float4*)&e8[0] = *(const float4*)(e + c0);
    *(float4*)&e8[4] = *(const float4*)(e + c0 + 4);
    #pragma unroll
    for (int k = 0; k < 4; ++k) {
        *(float4*)&c8[k][0] = *(const float4*)(c + k * DD + c0);
        *(float4*)&c8[k][4] = *(const float4*)(c + k * DD + c0 + 4);
    }
    #pragma unroll
    for (int r = 0; r < 8; ++r) {
        const size_t base = (size_t)(row0 + r) * DD + c0;
        float xv[8], o[8];
        *(float4*)&xv[0] = *(const float4*)(x + base);
        *(float4*)&xv[4] = *(const float4*)(x + base + 4);
        const float t0 = lt[0][r], t1 = lt[1][r], t2 = lt[2][r], t3 = lt[3][r];
        #pragma unroll
        for (int i = 0; i < 8; ++i) {
            float gg = a8[i];
            gg = fmaf(c8[0][i], t0, gg);
            gg = fmaf(c8[1][i], t1, gg);
            gg = fmaf(c8[2][i], t2, gg);
            gg = fmaf(c8[3][i], t3, gg);
            o[i] = fmaf(xv[i], gg, e8[i]);
        }
        *(float4*)(out + base)     = *(float4*)&o[0];
        *(float4*)(out + base + 4) = *(float4*)&o[4];
    }
}

extern "C" void kernel_launch(void* const* d_in, const int* in_sizes, int n_in,
                              void* d_out, int out_size, void* d_ws, size_t ws_size,
                              hipStream_t stream) {
    const float* x  = (const float*)d_in[0];   // [B, D]
    const float* w  = (const float*)d_in[1];   // [4, D]
    const float* bb = (const float*)d_in[2];   // [4, D]
    float* out = (float*)d_out;
    float* ws  = (float*)d_ws;
    float* partials = ws + OFF_P;
    float* mid      = ws + OFF_MID;

    k_pass<0><<<NB, PASS_THR, 0, stream>>>(x, w, ws);
    k_red_a<<<16 * 5 * 8, 256, 0, stream>>>(partials, mid, 5, 5 * 8);
    k_stats<0><<<8, 256, 0, stream>>>(ws, bb);

    k_pass<1><<<NB, PASS_THR, 0, stream>>>(x, w, ws);
    k_red_a<<<16 * 4 * 8, 256, 0, stream>>>(partials, mid, 4, 4 * 8);
    k_stats<1><<<8, 256, 0, stream>>>(ws, bb);

    k_pass<2><<<NB, PASS_THR, 0, stream>>>(x, w, ws);
    k_red_a<<<16 * 5 * 8, 256, 0, stream>>>(partials, mid, 5, 5 * 8);
    k_stats<2><<<8, 256, 0, stream>>>(ws, bb);

    k_pass<3><<<NB, PASS_THR, 0, stream>>>(x, w, ws);
    k_red_a<<<16 * 6 * 8, 256, 0, stream>>>(partials, mid, 6, 6 * 8);
    k_stats<3><<<8, 256, 0, stream>>>(ws, bb);

    k_final<<<BB / 8, 256, 0, stream>>>(x, ws, out);
}